// Round 6
// baseline (386.854 us; speedup 1.0000x reference)
//
#include <hip/hip_runtime.h>
#include <hip/hip_bf16.h>

// Grouped GEMM: out[e,s,o] = sum_i x[e,s,i] * w[e,o,i]
// E=8, S=8192 tok/expert, O=512, I=1024, fp32 in/out, bf16 MFMA compute.
// R6: A staged as fp32 via global_load_lds (DMA, no VGPR staging -> no spill
//     class), fp32->bf16 cvt at LDS-read time. Pre-swizzled global source +
//     matching XOR on ds_read (T2 both-sides). Counted vmcnt(8) + raw
//     s_barrier 2-phase (never drain to 0 mid-loop). B reg-direct from
//     packed Wpk (R3-proven), named register double-buffer.

#define NE 8
#define NO 512
#define NI 1024
#define NS 8192

#define BM 128
#define BN 128
#define BK 64
#define NT (NI / BK)  // 16 K-steps

typedef __attribute__((ext_vector_type(4))) float f32x4;
typedef __attribute__((ext_vector_type(8))) short short8;

__device__ __forceinline__ short8 cvt8(f32x4 a, f32x4 b) {
    short8 r;
    r[0] = (short)__builtin_bit_cast(unsigned short, __float2bfloat16(a[0]));
    r[1] = (short)__builtin_bit_cast(unsigned short, __float2bfloat16(a[1]));
    r[2] = (short)__builtin_bit_cast(unsigned short, __float2bfloat16(a[2]));
    r[3] = (short)__builtin_bit_cast(unsigned short, __float2bfloat16(a[3]));
    r[4] = (short)__builtin_bit_cast(unsigned short, __float2bfloat16(b[0]));
    r[5] = (short)__builtin_bit_cast(unsigned short, __float2bfloat16(b[1]));
    r[6] = (short)__builtin_bit_cast(unsigned short, __float2bfloat16(b[2]));
    r[7] = (short)__builtin_bit_cast(unsigned short, __float2bfloat16(b[3]));
    return r;
}

// ---- pass 0: W fp32 -> bf16, MFMA B-fragment lane order (verified R3/R5) ----
// Wpk(e, g, kt32, l, j) = bf16(W[e][g*16 + (l&15)][kt32*32 + (l>>4)*8 + j])
__global__ __launch_bounds__(256)
void pack_w(const float* __restrict__ W, short* __restrict__ Wpk) {
    int idx  = blockIdx.x * 256 + threadIdx.x;  // 0 .. 524287
    int l    = idx & 63;
    int kt32 = (idx >> 6) & 31;
    int g    = (idx >> 11) & 31;
    int e    = idx >> 16;
    const float* src = W + (size_t)(e * NO + g * 16 + (l & 15)) * NI
                         + kt32 * 32 + (l >> 4) * 8;
    f32x4 a = *(const f32x4*)src;
    f32x4 b = *(const f32x4*)(src + 4);
    *(short8*)(Wpk + (size_t)idx * 8) = cvt8(a, b);
}

// ---- main grouped GEMM ----
__global__ __launch_bounds__(256, 2)
void moe_gemm(const float* __restrict__ X,
              const short* __restrict__ Wpk,
              float* __restrict__ Out) {
    // 2048 blocks; XCD-chunk swizzle: each XCD owns one expert (W L2-resident).
    int bid  = blockIdx.x;
    int swz  = (bid & 7) * 256 + (bid >> 3);
    int e    = swz >> 8;
    int rem  = swz & 255;
    int mblk = rem >> 2;   // nblk inner: 4 siblings share the same A tile
    int nblk = rem & 3;

    const float* Ap = X   + ((size_t)e * NS + (size_t)mblk * BM) * NI;
    const short* Bp = Wpk + (size_t)e * (32 * 32 * 64 * 8);
    float*       Cp = Out + ((size_t)e * NS + (size_t)mblk * BM) * NO + nblk * BN;

    // A tile, fp32: 128 rows x 64 f32 (256 B/row) x 2 buffers = 64 KiB.
    __shared__ float lA[2][BM * BK];

    const int tid  = threadIdx.x;
    const int lane = tid & 63;
    const int wid  = tid >> 6;
    const int wr   = (wid >> 1) * 64;            // wave row base (2x2 wave grid)
    const int wc   = (wid & 1) * 64;             // wave col base
    const int wcg  = nblk * 8 + (wid & 1) * 4;   // B fragment-group base
    const int l15  = lane & 15;
    const int lhi  = lane >> 4;                  // 0..3

    f32x4 acc[4][4];
#pragma unroll
    for (int i = 0; i < 4; ++i)
#pragma unroll
        for (int j = 0; j < 4; ++j)
            acc[i][j] = (f32x4){0.f, 0.f, 0.f, 0.f};

    short8 bfrA[2][4], bfrB[2][4];   // named B double-buffer (rule #20)

    // A staging via global_load_lds: 1 KiB per inst = 4 rows x 256 B.
    // Lane l -> LDS byte l*16 => row = base + (l>>4), chunk = l&15.
    // Source pre-swizzle (T2 both-sides): global chunk = (l&15) ^ (row&15).
#define GLOADA(kt, buf)                                                        \
    do {                                                                       \
        _Pragma("unroll") for (int i = 0; i < 8; ++i) {                        \
            int rr = wid * 32 + i * 4 + lhi;                                   \
            int cs = l15 ^ ((i * 4 + lhi) & 15);                               \
            const float* gp = Ap + (size_t)rr * NI + (kt) * BK + cs * 4;       \
            float* lp = &lA[buf][(wid * 32 + i * 4) * BK];                     \
            __builtin_amdgcn_global_load_lds(                                  \
                (const __attribute__((address_space(1))) void*)gp,             \
                (__attribute__((address_space(3))) void*)lp, 16, 0, 0);        \
        }                                                                      \
    } while (0)

#define BLOAD(kt, dst)                                                         \
    do {                                                                       \
        _Pragma("unroll") for (int kk = 0; kk < 2; ++kk)                       \
            _Pragma("unroll") for (int ni = 0; ni < 4; ++ni)                   \
                dst[kk][ni] = *(const short8*)(Bp +                            \
                    ((size_t)((wcg + ni) * 32 + (kt) * 2 + kk) * 64 + lane) * 8); \
    } while (0)

    // Read side: fragment (mi,kk): row r = wr+mi*16+l15 (r&15 == l15),
    // f32 chunks gc = kk*8+lhi*2 {+0,+1}; phys = gc ^ l15.
#define COMPUTE(buf, bfr)                                                      \
    do {                                                                       \
        _Pragma("unroll") for (int kk = 0; kk < 2; ++kk) {                     \
            short8 af[4];                                                      \
            _Pragma("unroll") for (int mi = 0; mi < 4; ++mi) {                 \
                int r = wr + mi * 16 + l15;                                    \
                const char* base = (const char*)&lA[buf][0] + (size_t)r * 256; \
                int c0 = (kk * 8 + lhi * 2) ^ l15;                             \
                int c1 = (kk * 8 + lhi * 2 + 1) ^ l15;                         \
                f32x4 v0 = *(const f32x4*)(base + c0 * 16);                    \
                f32x4 v1 = *(const f32x4*)(base + c1 * 16);                    \
                af[mi] = cvt8(v0, v1);                                         \
            }                                                                  \
            _Pragma("unroll") for (int mi = 0; mi < 4; ++mi)                   \
                _Pragma("unroll") for (int ni = 0; ni < 4; ++ni)               \
                    acc[mi][ni] = __builtin_amdgcn_mfma_f32_16x16x32_bf16(     \
                        af[mi], bfr[kk][ni], acc[mi][ni], 0, 0, 0);            \
        }                                                                      \
    } while (0)

    // Prologue.
    GLOADA(0, 0);
    BLOAD(0, bfrA);
    asm volatile("s_waitcnt vmcnt(0)" ::: "memory");
    __builtin_amdgcn_s_barrier();

#pragma unroll 1
    for (int kt2 = 0; kt2 < NT / 2; ++kt2) {
        const int kt = kt2 * 2;
        // even phase: compute buf0/bfrA(kt); prefetch kt+1.
        BLOAD(kt + 1, bfrB);                                   // newest 8
        asm volatile("s_waitcnt vmcnt(8)" ::: "memory");       // gload(kt)+bload(kt) done
        __builtin_amdgcn_s_barrier();                          // all waves: buf0 ready, buf1 free
        GLOADA(kt + 1, 1);                                     // DMA into buf1, in flight across phase
        COMPUTE(0, bfrA);
        // odd phase: compute buf1/bfrB(kt+1); prefetch kt+2.
        if (kt2 < NT / 2 - 1) {
            BLOAD(kt + 2, bfrA);
            asm volatile("s_waitcnt vmcnt(8)" ::: "memory");
            __builtin_amdgcn_s_barrier();
            GLOADA(kt + 2, 0);
            COMPUTE(1, bfrB);
        } else {
            asm volatile("s_waitcnt vmcnt(0)" ::: "memory");   // final drain (once)
            __builtin_amdgcn_s_barrier();
            COMPUTE(1, bfrB);
        }
    }

    // Epilogue: D[m][n], m = (lane>>4)*4 + r, n = lane&15 per 16x16 frag (verified).
#pragma unroll
    for (int mi = 0; mi < 4; ++mi) {
#pragma unroll
        for (int r = 0; r < 4; ++r) {
            int row   = wr + mi * 16 + lhi * 4 + r;
            float* cp = Cp + (size_t)row * NO + wc + l15;
#pragma unroll
            for (int ni = 0; ni < 4; ++ni)
                cp[ni * 16] = acc[mi][ni][r];
        }
    }
#undef GLOADA
#undef BLOAD
#undef COMPUTE
}

extern "C" void kernel_launch(void* const* d_in, const int* in_sizes, int n_in,
                              void* d_out, int out_size, void* d_ws, size_t ws_size,
                              hipStream_t stream) {
    const float* X = (const float*)d_in[0];
    const float* W = (const float*)d_in[1];
    float* Out     = (float*)d_out;
    short* Wpk     = (short*)d_ws;   // 8 MiB

    hipLaunchKernelGGL(pack_w, dim3(2048), dim3(256), 0, stream, W, Wpk);
    hipLaunchKernelGGL(moe_gemm, dim3(NE * (NS / BM) * (NO / BN)), dim3(256), 0,
                       stream, X, Wpk, Out);
}

// Round 8
// 138.649 us; speedup vs baseline: 2.7902x; 2.7902x over previous
//
#include <hip/hip_runtime.h>
#include <hip/hip_bf16.h>

// Grouped GEMM: out[e,s,o] = sum_i x[e,s,i] * w[e,o,i]
// E=8, S=8192 tok/expert, O=512, I=1024, fp32 in/out, bf16 MFMA compute.
// R8 == R7 with the short4 name collision fixed (s16x4).
//     256x256 tile, 512 thr / 8 waves (2Mx4N), BK=64, LDS 128 KiB dbuf.
//     A: reg-staged fp32->bf16 (issue-early/write-late, counted vmcnt(4)).
//     B: row-major bf16 Wb (pass-0) via global_load_lds, pre-swizzled src.
//     Counted vmcnt(12) keeps new prefetches in flight across barriers.

#define NE 8
#define NO 512
#define NI 1024
#define NS 8192

#define BM 256
#define BN 256
#define BK 64
#define NT (NI / BK)  // 16 K-tiles

typedef __attribute__((ext_vector_type(4))) float f32x4;
typedef __attribute__((ext_vector_type(4))) short s16x4;
typedef __attribute__((ext_vector_type(8))) short s16x8;

__device__ __forceinline__ s16x4 cvt4(f32x4 a) {
    s16x4 r;
    r[0] = (short)__builtin_bit_cast(unsigned short, __float2bfloat16(a[0]));
    r[1] = (short)__builtin_bit_cast(unsigned short, __float2bfloat16(a[1]));
    r[2] = (short)__builtin_bit_cast(unsigned short, __float2bfloat16(a[2]));
    r[3] = (short)__builtin_bit_cast(unsigned short, __float2bfloat16(a[3]));
    return r;
}

// ---- pass 0: W fp32 -> bf16 row-major Wb[e][o][i] ----
__global__ __launch_bounds__(256)
void pack_w(const float* __restrict__ W, short* __restrict__ Wb) {
    size_t idx = (size_t)blockIdx.x * 256 + threadIdx.x;  // 524288 threads
    const float* src = W + idx * 8;
    f32x4 a = *(const f32x4*)src;
    f32x4 b = *(const f32x4*)(src + 4);
    s16x8 r;
    s16x4 lo = cvt4(a), hi = cvt4(b);
    r[0] = lo[0]; r[1] = lo[1]; r[2] = lo[2]; r[3] = lo[3];
    r[4] = hi[0]; r[5] = hi[1]; r[6] = hi[2]; r[7] = hi[3];
    *(s16x8*)(Wb + idx * 8) = r;
}

// ---- main grouped GEMM ----
__global__ __launch_bounds__(512, 2)
void moe_gemm(const float* __restrict__ X,
              const short* __restrict__ Wb,
              float* __restrict__ Out) {
    // 512 blocks = 8 e x 32 mblk x 2 nblk; XCD-chunk swizzle (512 = 8*64):
    // each XCD owns one expert -> W_e (1 MB bf16) L2-resident.
    int bid  = blockIdx.x;
    int swz  = (bid & 7) * 64 + (bid >> 3);
    int e    = swz >> 6;
    int rem  = swz & 63;
    int mblk = rem >> 1;
    int nblk = rem & 1;

    const float* Ap = X   + ((size_t)e * NS + (size_t)mblk * BM) * NI;
    const short* Bp = Wb  + ((size_t)e * NO + (size_t)nblk * BN) * NI;
    float*       Cp = Out + ((size_t)e * NS + (size_t)mblk * BM) * NO + nblk * BN;

    __shared__ short lA[2][BM * BK];   // 32 KiB each buf
    __shared__ short lB[2][BN * BK];   // total 128 KiB

    const int tid  = threadIdx.x;
    const int lane = tid & 63;
    const int wid  = tid >> 6;   // 0..7
    const int wm   = wid >> 2;   // 0..1  -> rows [wm*128, +128)
    const int wn   = wid & 3;    // 0..3  -> cols [wn*64, +64)
    const int l15  = lane & 15;
    const int lhi  = lane >> 4;  // 0..3

    f32x4 acc[8][4];
#pragma unroll
    for (int i = 0; i < 8; ++i)
#pragma unroll
        for (int j = 0; j < 4; ++j)
            acc[i][j] = (f32x4){0.f, 0.f, 0.f, 0.f};

    f32x4 ar[8];  // A staging regs: 8 x f32x4 = 32 floats/thread

    // A issue: unit u = tid + i*512 over 4096 f32x4-chunks of the 256x64 tile.
    // row = u>>4 (0..255), c4 = u&15 (f32x4 within 64-f32 row). Coalesced.
#define AISSUE(kt)                                                             \
    do {                                                                       \
        _Pragma("unroll") for (int i = 0; i < 8; ++i) {                        \
            int u = tid + i * 512;                                             \
            ar[i] = *(const f32x4*)(Ap + (size_t)(u >> 4) * NI +               \
                                    (kt) * BK + (u & 15) * 4);                 \
        }                                                                      \
    } while (0)

    // A write: chunk u -> 4 bf16 (8 B). 16B-chunk c16 = c4>>1, phys = c16^(row&7).
#define AWRITE(buf)                                                            \
    do {                                                                       \
        _Pragma("unroll") for (int i = 0; i < 8; ++i) {                        \
            int u    = tid + i * 512;                                          \
            int row  = u >> 4;                                                 \
            int c4   = u & 15;                                                 \
            int phys = (c4 >> 1) ^ (row & 7);                                  \
            *(s16x4*)&lA[buf][row * 64 + phys * 8 + (c4 & 1) * 4] = cvt4(ar[i]); \
        }                                                                      \
    } while (0)

    // B stage via global_load_lds: 4 instr/wave, 1 KiB each (lane*16B linear dest).
    // LDS 16B-chunk g = (wid*4+j)*64 + lane: row = g>>3, k16 = g&7.
    // Source pre-swizzled: logical chunk = k16 ^ (row&7)  (m173 both-sides).
#define BSTAGE(kt, buf)                                                        \
    do {                                                                       \
        _Pragma("unroll") for (int j = 0; j < 4; ++j) {                        \
            int g    = (wid * 4 + j) * 64 + lane;                              \
            int row  = g >> 3;                                                 \
            int k16  = g & 7;                                                  \
            const short* gp = Bp + (size_t)row * NI + (kt) * BK +              \
                              ((k16 ^ (row & 7)) << 3);                        \
            short* lp = &lB[buf][(wid * 4 + j) * 512];                         \
            __builtin_amdgcn_global_load_lds(                                  \
                (const __attribute__((address_space(1))) void*)gp,             \
                (__attribute__((address_space(3))) void*)lp, 16, 0, 0);        \
        }                                                                      \
    } while (0)

    // Fragment reads: row r, logical chunk kk*4+lhi, phys = logical ^ (r&7).
#define COMPUTE(buf)                                                           \
    do {                                                                       \
        _Pragma("unroll") for (int kk = 0; kk < 2; ++kk) {                     \
            s16x8 af[8], bf_[4];                                               \
            _Pragma("unroll") for (int mi = 0; mi < 8; ++mi) {                 \
                int r    = wm * 128 + mi * 16 + l15;                           \
                int phys = (kk * 4 + lhi) ^ (r & 7);                           \
                af[mi]   = *(const s16x8*)&lA[buf][r * 64 + phys * 8];         \
            }                                                                  \
            _Pragma("unroll") for (int ni = 0; ni < 4; ++ni) {                 \
                int rb   = wn * 64 + ni * 16 + l15;                            \
                int phys = (kk * 4 + lhi) ^ (rb & 7);                          \
                bf_[ni]  = *(const s16x8*)&lB[buf][rb * 64 + phys * 8];        \
            }                                                                  \
            _Pragma("unroll") for (int mi = 0; mi < 8; ++mi)                   \
                _Pragma("unroll") for (int ni = 0; ni < 4; ++ni)               \
                    acc[mi][ni] = __builtin_amdgcn_mfma_f32_16x16x32_bf16(     \
                        af[mi], bf_[ni], acc[mi][ni], 0, 0, 0);                \
        }                                                                      \
    } while (0)

    // Prologue: issue tile 0 (A first -> oldest, B second).
    AISSUE(0);        // 8 vm
    BSTAGE(0, 0);     // 4 vm

#pragma unroll 1
    for (int kt = 0; kt < NT; ++kt) {
        const int c = kt & 1;
        // B1: everyone done READING buf c (prev iter) -> safe to restage it.
        __builtin_amdgcn_s_barrier();
        // A(kt) regs ready (8 oldest drained); B(kt) DMA may stay in flight.
        asm volatile("s_waitcnt vmcnt(4)" ::: "memory");
        AWRITE(c);                                     // fp32->bf16 into lA[c]
        if (kt + 1 < NT) {
            AISSUE(kt + 1);                            // 8 vm (reuses ar)
            BSTAGE(kt + 1, c ^ 1);                     // 4 vm -> other buf
            // outstanding: B4(kt) + A8(kt+1) + B4(kt+1) = 16 -> drain B4(kt).
            asm volatile("s_waitcnt vmcnt(12)" ::: "memory");
        } else {
            asm volatile("s_waitcnt vmcnt(0)" ::: "memory");   // final drain
        }
        asm volatile("s_waitcnt lgkmcnt(0)" ::: "memory");     // my A writes done
        // B2: lA[c] + lB[c] fully staged for all waves.
        __builtin_amdgcn_s_barrier();
        COMPUTE(c);
    }

    // Epilogue: D frag (mi,ni): m = lhi*4 + rr, n = l15 (verified layout).
#pragma unroll
    for (int mi = 0; mi < 8; ++mi) {
#pragma unroll
        for (int rr = 0; rr < 4; ++rr) {
            int row   = wm * 128 + mi * 16 + lhi * 4 + rr;
            float* cp = Cp + (size_t)row * NO + wn * 64 + l15;
#pragma unroll
            for (int ni = 0; ni < 4; ++ni)
                cp[ni * 16] = acc[mi][ni][rr];
        }
    }
#undef AISSUE
#undef AWRITE
#undef BSTAGE
#undef COMPUTE
}

extern "C" void kernel_launch(void* const* d_in, const int* in_sizes, int n_in,
                              void* d_out, int out_size, void* d_ws, size_t ws_size,
                              hipStream_t stream) {
    const float* X = (const float*)d_in[0];
    const float* W = (const float*)d_in[1];
    float* Out     = (float*)d_out;
    short* Wb      = (short*)d_ws;   // 8 MiB bf16 W

    hipLaunchKernelGGL(pack_w, dim3(2048), dim3(256), 0, stream, W, Wb);
    hipLaunchKernelGGL(moe_gemm, dim3(NE * (NS / BM) * (NO / BN)), dim3(512), 0,
                       stream, X, Wb, Out);
}

// Round 9
// 127.542 us; speedup vs baseline: 3.0331x; 1.0871x over previous
//
#include <hip/hip_runtime.h>
#include <hip/hip_bf16.h>

// Grouped GEMM: out[e,s,o] = sum_i x[e,s,i] * w[e,o,i]
// E=8, S=8192 tok/expert, O=512, I=1024, fp32 in/out, bf16 MFMA compute.
// R9: 8-phase port of R8 (T3+T4+T5 on the proven 256x256/BK64/8-wave frame).
//     4 phases per K-tile, 16 MFMA per phase, staging distributed:
//       P1: vmcnt(4) A[0-3]rdy -> AWRITE_H1 + BSTAGE(kt+1) | read bf(kk0)+af03
//       P2: vmcnt(4) A[4-7]rdy -> AWRITE_H2 + AISSUE_H1(kt+2) | read af47
//       P3: AISSUE_H2(kt+2) | read bf(kk1)+af03
//       P4: vmcnt(8) drain B-DMA keep A8 | read af47
//     Each phase: bar; lgkmcnt(0); setprio(1); 16 MFMA; setprio(0); bar.
//     Single ar[8] A-buffer, 3-phase load->consume lead. Never vmcnt(0) in loop.

#define NE 8
#define NO 512
#define NI 1024
#define NS 8192

#define BM 256
#define BN 256
#define BK 64
#define NT (NI / BK)  // 16 K-tiles

typedef __attribute__((ext_vector_type(4))) float f32x4;
typedef __attribute__((ext_vector_type(4))) short s16x4;
typedef __attribute__((ext_vector_type(8))) short s16x8;

__device__ __forceinline__ s16x4 cvt4(f32x4 a) {
    s16x4 r;
    r[0] = (short)__builtin_bit_cast(unsigned short, __float2bfloat16(a[0]));
    r[1] = (short)__builtin_bit_cast(unsigned short, __float2bfloat16(a[1]));
    r[2] = (short)__builtin_bit_cast(unsigned short, __float2bfloat16(a[2]));
    r[3] = (short)__builtin_bit_cast(unsigned short, __float2bfloat16(a[3]));
    return r;
}

// ---- pass 0: W fp32 -> bf16 row-major Wb[e][o][i] ----
__global__ __launch_bounds__(256)
void pack_w(const float* __restrict__ W, short* __restrict__ Wb) {
    size_t idx = (size_t)blockIdx.x * 256 + threadIdx.x;  // 524288 threads
    const float* src = W + idx * 8;
    f32x4 a = *(const f32x4*)src;
    f32x4 b = *(const f32x4*)(src + 4);
    s16x8 r;
    s16x4 lo = cvt4(a), hi = cvt4(b);
    r[0] = lo[0]; r[1] = lo[1]; r[2] = lo[2]; r[3] = lo[3];
    r[4] = hi[0]; r[5] = hi[1]; r[6] = hi[2]; r[7] = hi[3];
    *(s16x8*)(Wb + idx * 8) = r;
}

// ---- main grouped GEMM ----
__global__ __launch_bounds__(512, 1)
void moe_gemm(const float* __restrict__ X,
              const short* __restrict__ Wb,
              float* __restrict__ Out) {
    // 512 blocks = 8 e x 32 mblk x 2 nblk; XCD-chunk swizzle: one expert/XCD.
    int bid  = blockIdx.x;
    int swz  = (bid & 7) * 64 + (bid >> 3);
    int e    = swz >> 6;
    int rem  = swz & 63;
    int mblk = rem >> 1;
    int nblk = rem & 1;

    const float* Ap = X   + ((size_t)e * NS + (size_t)mblk * BM) * NI;
    const short* Bp = Wb  + ((size_t)e * NO + (size_t)nblk * BN) * NI;
    float*       Cp = Out + ((size_t)e * NS + (size_t)mblk * BM) * NO + nblk * BN;

    __shared__ short lA[2][BM * BK];   // 32 KiB each buf
    __shared__ short lB[2][BN * BK];   // total 128 KiB

    const int tid  = threadIdx.x;
    const int lane = tid & 63;
    const int wid  = tid >> 6;   // 0..7
    const int wm   = wid >> 2;   // 0..1  -> rows [wm*128, +128)
    const int wn   = wid & 3;    // 0..3  -> cols [wn*64, +64)
    const int l15  = lane & 15;
    const int lhi  = lane >> 4;  // 0..3

    f32x4 acc[8][4];
#pragma unroll
    for (int i = 0; i < 8; ++i)
#pragma unroll
        for (int j = 0; j < 4; ++j)
            acc[i][j] = (f32x4){0.f, 0.f, 0.f, 0.f};

    f32x4 ar[8];   // single A staging buffer, halves staggered
    s16x8 af[4], bf_[4];

    // A chunks: u = tid + i*512; row = u>>4 (0..255), c4 = u&15. Coalesced.
#define AISSUE_H(kt, h)                                                        \
    do {                                                                       \
        _Pragma("unroll") for (int i = (h) * 4; i < (h) * 4 + 4; ++i) {        \
            int u = tid + i * 512;                                             \
            ar[i] = *(const f32x4*)(Ap + (size_t)(u >> 4) * NI +               \
                                    (kt) * BK + (u & 15) * 4);                 \
        }                                                                      \
    } while (0)

    // A write: 16B-chunk c16 = c4>>1, phys = c16 ^ (row&7).
#define AWRITE_H(buf, h)                                                       \
    do {                                                                       \
        _Pragma("unroll") for (int i = (h) * 4; i < (h) * 4 + 4; ++i) {        \
            int u    = tid + i * 512;                                          \
            int row  = u >> 4;                                                 \
            int c4   = u & 15;                                                 \
            int phys = (c4 >> 1) ^ (row & 7);                                  \
            *(s16x4*)&lA[buf][row * 64 + phys * 8 + (c4 & 1) * 4] = cvt4(ar[i]); \
        }                                                                      \
    } while (0)

    // B stage via global_load_lds, linear dest, pre-swizzled source (m173).
#define BSTAGE(kt, buf)                                                        \
    do {                                                                       \
        _Pragma("unroll") for (int j = 0; j < 4; ++j) {                        \
            int g    = (wid * 4 + j) * 64 + lane;                              \
            int row  = g >> 3;                                                 \
            int k16  = g & 7;                                                  \
            const short* gp = Bp + (size_t)row * NI + (kt) * BK +              \
                              ((k16 ^ (row & 7)) << 3);                        \
            short* lp = &lB[buf][(wid * 4 + j) * 512];                         \
            __builtin_amdgcn_global_load_lds(                                  \
                (const __attribute__((address_space(1))) void*)gp,             \
                (__attribute__((address_space(3))) void*)lp, 16, 0, 0);        \
        }                                                                      \
    } while (0)

#define PH_READ_A(c, kk, mh)                                                   \
    do {                                                                       \
        _Pragma("unroll") for (int j = 0; j < 4; ++j) {                        \
            int r    = wm * 128 + ((mh) * 4 + j) * 16 + l15;                   \
            int phys = ((kk) * 4 + lhi) ^ (r & 7);                             \
            af[j]    = *(const s16x8*)&lA[c][r * 64 + phys * 8];               \
        }                                                                      \
    } while (0)

#define PH_READ_B(c, kk)                                                       \
    do {                                                                       \
        _Pragma("unroll") for (int ni = 0; ni < 4; ++ni) {                     \
            int rb   = wn * 64 + ni * 16 + l15;                                \
            int phys = ((kk) * 4 + lhi) ^ (rb & 7);                            \
            bf_[ni]  = *(const s16x8*)&lB[c][rb * 64 + phys * 8];              \
        }                                                                      \
    } while (0)

#define PH_MFMA(mh)                                                            \
    do {                                                                       \
        __builtin_amdgcn_s_setprio(1);                                         \
        _Pragma("unroll") for (int j = 0; j < 4; ++j)                          \
            _Pragma("unroll") for (int ni = 0; ni < 4; ++ni)                   \
                acc[(mh) * 4 + j][ni] = __builtin_amdgcn_mfma_f32_16x16x32_bf16( \
                    af[j], bf_[ni], acc[(mh) * 4 + j][ni], 0, 0, 0);           \
        __builtin_amdgcn_s_setprio(0);                                         \
    } while (0)

#define BAR()   __builtin_amdgcn_s_barrier()
#define LGKM0() asm volatile("s_waitcnt lgkmcnt(0)" ::: "memory")

    // ---- Prologue: stage tile 0; leave A8(1) in flight (invariant). ----
    AISSUE_H(0, 0); AISSUE_H(0, 1);
    asm volatile("s_waitcnt vmcnt(0)" ::: "memory");
    AWRITE_H(0, 0); AWRITE_H(0, 1);
    BSTAGE(0, 0);                       // B4(0) in flight
    AISSUE_H(1, 0); AISSUE_H(1, 1);     // A8(1) in flight
    LGKM0();                            // my A ds_writes visible
    asm volatile("s_waitcnt vmcnt(8)" ::: "memory");   // drain B4(0), keep A8(1)
    BAR();

#pragma unroll 1
    for (int kt = 0; kt < NT; ++kt) {
        const int c = kt & 1;
        // ---- P1: kk0, mi 0-3 ----
        asm volatile("s_waitcnt vmcnt(4)" ::: "memory");   // ar[0-3] = A(kt+1) ready
        if (kt + 1 < NT) {
            AWRITE_H(c ^ 1, 0);
            BSTAGE(kt + 1, c ^ 1);
        }
        PH_READ_B(c, 0);
        PH_READ_A(c, 0, 0);
        BAR(); LGKM0();
        PH_MFMA(0);
        BAR();
        // ---- P2: kk0, mi 4-7 ----
        asm volatile("s_waitcnt vmcnt(4)" ::: "memory");   // ar[4-7] ready, keep B4
        if (kt + 1 < NT) AWRITE_H(c ^ 1, 1);
        if (kt + 2 < NT) AISSUE_H(kt + 2, 0);
        PH_READ_A(c, 0, 1);
        BAR(); LGKM0();
        PH_MFMA(1);
        BAR();
        // ---- P3: kk1, mi 0-3 ----
        if (kt + 2 < NT) AISSUE_H(kt + 2, 1);
        PH_READ_B(c, 1);
        PH_READ_A(c, 1, 0);
        BAR(); LGKM0();
        PH_MFMA(0);
        BAR();
        // ---- P4: kk1, mi 4-7 ----
        PH_READ_A(c, 1, 1);
        if (kt + 2 < NT) { asm volatile("s_waitcnt vmcnt(8)" ::: "memory"); }
        else             { asm volatile("s_waitcnt vmcnt(0)" ::: "memory"); }
        BAR(); LGKM0();
        PH_MFMA(1);
        BAR();
    }

    // Epilogue: D frag (mi,ni): m = lhi*4 + rr, n = l15 (verified layout).
#pragma unroll
    for (int mi = 0; mi < 8; ++mi) {
#pragma unroll
        for (int rr = 0; rr < 4; ++rr) {
            int row   = wm * 128 + mi * 16 + lhi * 4 + rr;
            float* cp = Cp + (size_t)row * NO + wn * 64 + l15;
#pragma unroll
            for (int ni = 0; ni < 4; ++ni)
                cp[ni * 16] = acc[mi][ni][rr];
        }
    }
#undef AISSUE_H
#undef AWRITE_H
#undef BSTAGE
#undef PH_READ_A
#undef PH_READ_B
#undef PH_MFMA
#undef BAR
#undef LGKM0
}

extern "C" void kernel_launch(void* const* d_in, const int* in_sizes, int n_in,
                              void* d_out, int out_size, void* d_ws, size_t ws_size,
                              hipStream_t stream) {
    const float* X = (const float*)d_in[0];
    const float* W = (const float*)d_in[1];
    float* Out     = (float*)d_out;
    short* Wb      = (short*)d_ws;   // 8 MiB bf16 W

    hipLaunchKernelGGL(pack_w, dim3(2048), dim3(256), 0, stream, W, Wb);
    hipLaunchKernelGGL(moe_gemm, dim3(NE * (NS / BM) * (NO / BN)), dim3(512), 0,
                       stream, X, Wb, Out);
}